// Round 4
// baseline (238.186 us; speedup 1.0000x reference)
//
#include <hip/hip_runtime.h>

#define ETA_PLUS 1.2f
#define ETA_MINUS 0.5f
#define STEP_MIN 1e-6f
#define STEP_MAX 50.0f

typedef float vfloat4 __attribute__((ext_vector_type(4)));

__device__ __forceinline__ void irprop_elem(
    float p, float g, float s, float pg, float pu, bool loss_inc,
    float& new_p, float& new_s, float& new_pg, float& new_u)
{
    float sign = g * pg;
    float ns;
    if (sign > 0.0f)       ns = fminf(s * ETA_PLUS, STEP_MAX);
    else if (sign < 0.0f)  ns = fmaxf(s * ETA_MINUS, STEP_MIN);
    else                   ns = s;

    bool neg = (sign < 0.0f);
    float geff = (g > 0.0f) ? 1.0f : ((g < 0.0f) ? -1.0f : 0.0f);
    float upd = -ns * geff;
    if (neg) upd = loss_inc ? -pu : 0.0f;

    new_p  = p + upd;
    new_s  = ns;
    new_pg = neg ? 0.0f : g;
    new_u  = upd;
}

__device__ __forceinline__ void irprop_vec4(
    vfloat4 p, vfloat4 g, vfloat4 s, vfloat4 pg, vfloat4 pu, bool loss_inc,
    vfloat4& rp, vfloat4& rs, vfloat4& rpg, vfloat4& ru)
{
    #pragma unroll
    for (int j = 0; j < 4; ++j) {
        float a, b, c, d;
        irprop_elem(p[j], g[j], s[j], pg[j], pu[j], loss_inc, a, b, c, d);
        rp[j] = a; rs[j] = b; rpg[j] = c; ru[j] = d;
    }
}

// Each thread handles bundles i and i+half: 10 nt loads in flight before any
// use -> deeper MLP against 9-stream row-thrash; 8x fewer blocks.
__global__ __launch_bounds__(256) void irprop_kernel(
    const vfloat4* __restrict__ param,
    const vfloat4* __restrict__ grad,
    const vfloat4* __restrict__ stepsz,
    const vfloat4* __restrict__ pgrad,
    const vfloat4* __restrict__ pupd,
    const float* __restrict__ loss,
    const float* __restrict__ ploss,
    vfloat4* __restrict__ out,   // [new_param | step_new | new_prev_grad | update]
    int half, int n4)
{
    const int i = blockIdx.x * blockDim.x + threadIdx.x;
    if (i >= half) return;
    const int i2 = i + half;

    const bool loss_inc = (loss[0] > ploss[0]);  // uniform, cached broadcast

    // issue all 10 streaming loads back-to-back
    vfloat4 p0  = __builtin_nontemporal_load(&param[i]);
    vfloat4 g0  = __builtin_nontemporal_load(&grad[i]);
    vfloat4 s0  = __builtin_nontemporal_load(&stepsz[i]);
    vfloat4 pg0 = __builtin_nontemporal_load(&pgrad[i]);
    vfloat4 pu0 = __builtin_nontemporal_load(&pupd[i]);
    vfloat4 p1  = __builtin_nontemporal_load(&param[i2]);
    vfloat4 g1  = __builtin_nontemporal_load(&grad[i2]);
    vfloat4 s1  = __builtin_nontemporal_load(&stepsz[i2]);
    vfloat4 pg1 = __builtin_nontemporal_load(&pgrad[i2]);
    vfloat4 pu1 = __builtin_nontemporal_load(&pupd[i2]);

    vfloat4 rp0, rs0, rpg0, ru0, rp1, rs1, rpg1, ru1;
    irprop_vec4(p0, g0, s0, pg0, pu0, loss_inc, rp0, rs0, rpg0, ru0);
    irprop_vec4(p1, g1, s1, pg1, pu1, loss_inc, rp1, rs1, rpg1, ru1);

    __builtin_nontemporal_store(rp0,  &out[i]);
    __builtin_nontemporal_store(rs0,  &out[(size_t)n4 + i]);
    __builtin_nontemporal_store(rpg0, &out[2 * (size_t)n4 + i]);
    __builtin_nontemporal_store(ru0,  &out[3 * (size_t)n4 + i]);
    __builtin_nontemporal_store(rp1,  &out[i2]);
    __builtin_nontemporal_store(rs1,  &out[(size_t)n4 + i2]);
    __builtin_nontemporal_store(rpg1, &out[2 * (size_t)n4 + i2]);
    __builtin_nontemporal_store(ru1,  &out[3 * (size_t)n4 + i2]);
}

extern "C" void kernel_launch(void* const* d_in, const int* in_sizes, int n_in,
                              void* d_out, int out_size, void* d_ws, size_t ws_size,
                              hipStream_t stream) {
    const float* param  = (const float*)d_in[0];
    const float* grad   = (const float*)d_in[1];
    const float* stepsz = (const float*)d_in[2];
    const float* pgrad  = (const float*)d_in[3];
    const float* pupd   = (const float*)d_in[4];
    const float* loss   = (const float*)d_in[5];
    const float* ploss  = (const float*)d_in[6];

    int n    = in_sizes[0];
    int n4   = n / 4;   // N = 2^25 -> n4 = 2^23
    int half = n4 / 2;  // 2 bundles per thread

    const int block = 256;
    int grid = (half + block - 1) / block;

    irprop_kernel<<<grid, block, 0, stream>>>(
        (const vfloat4*)param, (const vfloat4*)grad, (const vfloat4*)stepsz,
        (const vfloat4*)pgrad, (const vfloat4*)pupd,
        loss, ploss, (vfloat4*)d_out, half, n4);
}

// Round 5
// 212.288 us; speedup vs baseline: 1.1220x; 1.1220x over previous
//
#include <hip/hip_runtime.h>

#define ETA_PLUS 1.2f
#define ETA_MINUS 0.5f
#define STEP_MIN 1e-6f
#define STEP_MAX 50.0f

typedef float vfloat4 __attribute__((ext_vector_type(4)));

__device__ __forceinline__ void irprop_elem(
    float p, float g, float s, float pg, float pu, bool loss_inc,
    float& new_p, float& new_s, float& new_pg, float& new_u)
{
    float sign = g * pg;
    float ns;
    if (sign > 0.0f)       ns = fminf(s * ETA_PLUS, STEP_MAX);
    else if (sign < 0.0f)  ns = fmaxf(s * ETA_MINUS, STEP_MIN);
    else                   ns = s;

    bool neg = (sign < 0.0f);
    float geff = (g > 0.0f) ? 1.0f : ((g < 0.0f) ? -1.0f : 0.0f);
    float upd = -ns * geff;
    if (neg) upd = loss_inc ? -pu : 0.0f;

    new_p  = p + upd;
    new_s  = ns;
    new_pg = neg ? 0.0f : g;
    new_u  = upd;
}

__device__ __forceinline__ void irprop_vec4(
    vfloat4 p, vfloat4 g, vfloat4 s, vfloat4 pg, vfloat4 pu, bool loss_inc,
    vfloat4& rp, vfloat4& rs, vfloat4& rpg, vfloat4& ru)
{
    #pragma unroll
    for (int j = 0; j < 4; ++j) {
        float a, b, c, d;
        irprop_elem(p[j], g[j], s[j], pg[j], pu[j], loss_inc, a, b, c, d);
        rp[j] = a; rs[j] = b; rpg[j] = c; ru[j] = d;
    }
}

// 2 bundles/thread, BLOCK-ADJACENT (i and i+blockDim): block covers one
// contiguous 8KB chunk per stream -> 9 macro-streams preserved (R4's split
// at n4/2 made 18 streams and regressed), while still putting 10 nt loads
// in flight per thread.
__global__ __launch_bounds__(256) void irprop_kernel(
    const vfloat4* __restrict__ param,
    const vfloat4* __restrict__ grad,
    const vfloat4* __restrict__ stepsz,
    const vfloat4* __restrict__ pgrad,
    const vfloat4* __restrict__ pupd,
    const float* __restrict__ loss,
    const float* __restrict__ ploss,
    vfloat4* __restrict__ out,   // [new_param | step_new | new_prev_grad | update]
    int n4)
{
    const int i1 = blockIdx.x * (2 * blockDim.x) + threadIdx.x;
    const int i2 = i1 + blockDim.x;
    if (i2 >= n4) return;  // exact-sized grid: never taken, keeps compiler honest

    const bool loss_inc = (loss[0] > ploss[0]);  // uniform, cached broadcast

    vfloat4 p0  = __builtin_nontemporal_load(&param[i1]);
    vfloat4 g0  = __builtin_nontemporal_load(&grad[i1]);
    vfloat4 s0  = __builtin_nontemporal_load(&stepsz[i1]);
    vfloat4 pg0 = __builtin_nontemporal_load(&pgrad[i1]);
    vfloat4 pu0 = __builtin_nontemporal_load(&pupd[i1]);
    vfloat4 p1  = __builtin_nontemporal_load(&param[i2]);
    vfloat4 g1  = __builtin_nontemporal_load(&grad[i2]);
    vfloat4 s1  = __builtin_nontemporal_load(&stepsz[i2]);
    vfloat4 pg1 = __builtin_nontemporal_load(&pgrad[i2]);
    vfloat4 pu1 = __builtin_nontemporal_load(&pupd[i2]);

    vfloat4 rp0, rs0, rpg0, ru0, rp1, rs1, rpg1, ru1;
    irprop_vec4(p0, g0, s0, pg0, pu0, loss_inc, rp0, rs0, rpg0, ru0);
    irprop_vec4(p1, g1, s1, pg1, pu1, loss_inc, rp1, rs1, rpg1, ru1);

    __builtin_nontemporal_store(rp0,  &out[i1]);
    __builtin_nontemporal_store(rs0,  &out[(size_t)n4 + i1]);
    __builtin_nontemporal_store(rpg0, &out[2 * (size_t)n4 + i1]);
    __builtin_nontemporal_store(ru0,  &out[3 * (size_t)n4 + i1]);
    __builtin_nontemporal_store(rp1,  &out[i2]);
    __builtin_nontemporal_store(rs1,  &out[(size_t)n4 + i2]);
    __builtin_nontemporal_store(rpg1, &out[2 * (size_t)n4 + i2]);
    __builtin_nontemporal_store(ru1,  &out[3 * (size_t)n4 + i2]);
}

extern "C" void kernel_launch(void* const* d_in, const int* in_sizes, int n_in,
                              void* d_out, int out_size, void* d_ws, size_t ws_size,
                              hipStream_t stream) {
    const float* param  = (const float*)d_in[0];
    const float* grad   = (const float*)d_in[1];
    const float* stepsz = (const float*)d_in[2];
    const float* pgrad  = (const float*)d_in[3];
    const float* pupd   = (const float*)d_in[4];
    const float* loss   = (const float*)d_in[5];
    const float* ploss  = (const float*)d_in[6];

    int n  = in_sizes[0];
    int n4 = n / 4;  // N = 2^25 -> n4 = 2^23, divisible by 512

    const int block = 256;
    int grid = n4 / (2 * block);  // exact: each block handles 512 contiguous bundles

    irprop_kernel<<<grid, block, 0, stream>>>(
        (const vfloat4*)param, (const vfloat4*)grad, (const vfloat4*)stepsz,
        (const vfloat4*)pgrad, (const vfloat4*)pupd,
        loss, ploss, (vfloat4*)d_out, n4);
}

// Round 6
// 211.957 us; speedup vs baseline: 1.1237x; 1.0016x over previous
//
#include <hip/hip_runtime.h>

#define ETA_PLUS 1.2f
#define ETA_MINUS 0.5f
#define STEP_MIN 1e-6f
#define STEP_MAX 50.0f

typedef float vfloat4 __attribute__((ext_vector_type(4)));

__device__ __forceinline__ void irprop_elem(
    float p, float g, float s, float pg, float pu, bool loss_inc,
    float& new_p, float& new_s, float& new_pg, float& new_u)
{
    float sign = g * pg;
    float ns;
    if (sign > 0.0f)       ns = fminf(s * ETA_PLUS, STEP_MAX);
    else if (sign < 0.0f)  ns = fmaxf(s * ETA_MINUS, STEP_MIN);
    else                   ns = s;

    bool neg = (sign < 0.0f);
    float geff = (g > 0.0f) ? 1.0f : ((g < 0.0f) ? -1.0f : 0.0f);
    float upd = -ns * geff;
    if (neg) upd = loss_inc ? -pu : 0.0f;

    new_p  = p + upd;
    new_s  = ns;
    new_pg = neg ? 0.0f : g;
    new_u  = upd;
}

__device__ __forceinline__ void irprop_vec4(
    vfloat4 p, vfloat4 g, vfloat4 s, vfloat4 pg, vfloat4 pu, bool loss_inc,
    vfloat4& rp, vfloat4& rs, vfloat4& rpg, vfloat4& ru)
{
    #pragma unroll
    for (int j = 0; j < 4; ++j) {
        float a, b, c, d;
        irprop_elem(p[j], g[j], s[j], pg[j], pu[j], loss_inc, a, b, c, d);
        rp[j] = a; rs[j] = b; rpg[j] = c; ru[j] = d;
    }
}

// 4 block-adjacent bundles/thread (i, i+B, i+2B, i+3B): 20 nt loads in
// flight, block covers one contiguous 16KB chunk per stream, global pattern
// stays 9 macro-streams (R4 lesson: never split streams; R5 lesson: MLP
// depth within a stream is a real win).
__global__ __launch_bounds__(256) void irprop_kernel(
    const vfloat4* __restrict__ param,
    const vfloat4* __restrict__ grad,
    const vfloat4* __restrict__ stepsz,
    const vfloat4* __restrict__ pgrad,
    const vfloat4* __restrict__ pupd,
    const float* __restrict__ loss,
    const float* __restrict__ ploss,
    vfloat4* __restrict__ out,   // [new_param | step_new | new_prev_grad | update]
    int n4)
{
    const int base = blockIdx.x * (4 * 256) + threadIdx.x;
    const bool loss_inc = (loss[0] > ploss[0]);  // uniform, cached broadcast

    vfloat4 p[4], g[4], s[4], pg[4], pu[4];
    #pragma unroll
    for (int k = 0; k < 4; ++k) {
        const int i = base + k * 256;
        p[k]  = __builtin_nontemporal_load(&param[i]);
        g[k]  = __builtin_nontemporal_load(&grad[i]);
        s[k]  = __builtin_nontemporal_load(&stepsz[i]);
        pg[k] = __builtin_nontemporal_load(&pgrad[i]);
        pu[k] = __builtin_nontemporal_load(&pupd[i]);
    }

    vfloat4 rp[4], rs[4], rpg[4], ru[4];
    #pragma unroll
    for (int k = 0; k < 4; ++k)
        irprop_vec4(p[k], g[k], s[k], pg[k], pu[k], loss_inc,
                    rp[k], rs[k], rpg[k], ru[k]);

    #pragma unroll
    for (int k = 0; k < 4; ++k) {
        const int i = base + k * 256;
        __builtin_nontemporal_store(rp[k],  &out[i]);
        __builtin_nontemporal_store(rs[k],  &out[(size_t)n4 + i]);
        __builtin_nontemporal_store(rpg[k], &out[2 * (size_t)n4 + i]);
        __builtin_nontemporal_store(ru[k],  &out[3 * (size_t)n4 + i]);
    }
}

extern "C" void kernel_launch(void* const* d_in, const int* in_sizes, int n_in,
                              void* d_out, int out_size, void* d_ws, size_t ws_size,
                              hipStream_t stream) {
    const float* param  = (const float*)d_in[0];
    const float* grad   = (const float*)d_in[1];
    const float* stepsz = (const float*)d_in[2];
    const float* pgrad  = (const float*)d_in[3];
    const float* pupd   = (const float*)d_in[4];
    const float* loss   = (const float*)d_in[5];
    const float* ploss  = (const float*)d_in[6];

    int n  = in_sizes[0];
    int n4 = n / 4;  // N = 2^25 -> n4 = 2^23, divisible by 1024

    const int block = 256;
    int grid = n4 / (4 * block);  // 8192 blocks, each owns 1024 contiguous bundles

    irprop_kernel<<<grid, block, 0, stream>>>(
        (const vfloat4*)param, (const vfloat4*)grad, (const vfloat4*)stepsz,
        (const vfloat4*)pgrad, (const vfloat4*)pupd,
        loss, ploss, (vfloat4*)d_out, n4);
}